// Round 2
// baseline (474.209 us; speedup 1.0000x reference)
//
#include <hip/hip_runtime.h>

#define N_NODES 100000
#define T_P 12
#define C_H 32
#define E_EDGES 3200000

#define NODES_PER_B 256
#define NB 391                    // ceil(100000/256) buckets
#define LSTR 13                   // LDS row stride (odd -> bank spread)

#define VEC_E (E_EDGES / 4)       // 800000 int4/float4 vectors
#define P1_THREADS 512
#define P1_VECS 2048              // vectors per block in phase 1
#define NBLK1 ((VEC_E + P1_VECS - 1) / P1_VECS)   // 391

// ws layout (4-byte units from d_ws):
//   P[256] | dinv[N] | cnt[NB] | base[NB+1] | cursor[NB] | y[N*16] | entries[E]{float2}
// total ~33 MB

__global__ void zero_cnt_kernel(int* __restrict__ cnt) {
    int i = threadIdx.x;
    if (i < NB) cnt[i] = 0;
}

__global__ void params_kernel(const float* __restrict__ wz, const float* __restrict__ bz,
                              const float* __restrict__ wh, const float* __restrict__ bh,
                              const float* __restrict__ lwz, const float* __restrict__ lbz,
                              const float* __restrict__ lwh, const float* __restrict__ lbh,
                              const float* __restrict__ att, float* __restrict__ P) {
    int o = threadIdx.x;
    if (o < C_H) {
        float az = 0.f, bzv = 0.f, ah = 0.f, bhv = 0.f;
        for (int c = 0; c < C_H; ++c) {
            float lz = lwz[o * 2 * C_H + c];
            float lh = lwh[o * 2 * C_H + c];
            az += wz[c] * lz;  bzv += bz[c] * lz;
            ah += wh[c] * lh;  bhv += bh[c] * lh;
        }
        P[16 + o]  = az;  P[48 + o]  = bzv + lbz[o];
        P[80 + o]  = ah;  P[112 + o] = bhv + lbh[o];
    }
    if (o == 0) {
        float m = -1e30f;
        for (int t = 0; t < T_P; ++t) m = fmaxf(m, att[t]);
        float e[T_P], s = 0.f;
        for (int t = 0; t < T_P; ++t) { e[t] = __expf(att[t] - m); s += e[t]; }
        float inv = 1.0f / s;
        for (int t = 0; t < T_P; ++t) P[t] = e[t] * inv;
    }
}

// Phase 1a: coarse histogram of dst>>8 with LDS privatization.
__global__ void bucket_count_kernel(const int* __restrict__ dst, int* __restrict__ cnt) {
    __shared__ int h[NB];
    for (int i = threadIdx.x; i < NB; i += P1_THREADS) h[i] = 0;
    __syncthreads();
    const int4* d4 = (const int4*)dst;
    int vbase = blockIdx.x * P1_VECS;
#pragma unroll
    for (int k = 0; k < 4; ++k) {
        int v = vbase + threadIdx.x + k * P1_THREADS;
        if (v < VEC_E) {
            int4 d = d4[v];
            atomicAdd(&h[d.x >> 8], 1);
            atomicAdd(&h[d.y >> 8], 1);
            atomicAdd(&h[d.z >> 8], 1);
            atomicAdd(&h[d.w >> 8], 1);
        }
    }
    __syncthreads();
    for (int i = threadIdx.x; i < NB; i += P1_THREADS) {
        int c = h[i];
        if (c) atomicAdd(&cnt[i], c);
    }
}

// exclusive scan of NB bucket counts -> base + cursor copy
__global__ void bucket_scan_kernel(const int* __restrict__ cnt, int* __restrict__ basea,
                                   int* __restrict__ cursor) {
    __shared__ int buf[512];
    int tid = threadIdx.x;
    int v = (tid < NB) ? cnt[tid] : 0;
    buf[tid] = v;
    __syncthreads();
    for (int d = 1; d < 512; d <<= 1) {
        int t = (tid >= d) ? buf[tid - d] : 0;
        __syncthreads();
        buf[tid] += t;
        __syncthreads();
    }
    if (tid < NB) {
        int ex = buf[tid] - v;
        basea[tid] = ex;
        cursor[tid] = ex;
    }
    if (tid == 0) basea[NB] = E_EDGES;
}

// Phase 1b: per-block recount -> claim ranges -> scatter {src | d_local<<17, w}
__global__ void bucket_scatter_kernel(const int* __restrict__ src, const int* __restrict__ dst,
                                      const float* __restrict__ w, int* __restrict__ cursor,
                                      float2* __restrict__ entries) {
    __shared__ int h[NB];
    __shared__ int claim[NB];
    for (int i = threadIdx.x; i < NB; i += P1_THREADS) h[i] = 0;
    __syncthreads();
    const int4* d4 = (const int4*)dst;
    int vbase = blockIdx.x * P1_VECS;
    int4 dc[4];
#pragma unroll
    for (int k = 0; k < 4; ++k) {
        int v = vbase + threadIdx.x + k * P1_THREADS;
        if (v < VEC_E) {
            int4 d = d4[v];
            dc[k] = d;
            atomicAdd(&h[d.x >> 8], 1);
            atomicAdd(&h[d.y >> 8], 1);
            atomicAdd(&h[d.z >> 8], 1);
            atomicAdd(&h[d.w >> 8], 1);
        }
    }
    __syncthreads();
    for (int i = threadIdx.x; i < NB; i += P1_THREADS) {
        int c = h[i];
        claim[i] = c ? atomicAdd(&cursor[i], c) : 0;
    }
    __syncthreads();
    for (int i = threadIdx.x; i < NB; i += P1_THREADS) h[i] = 0;   // reuse as rank counter
    __syncthreads();
    const int4* s4 = (const int4*)src;
    const float4* w4 = (const float4*)w;
#pragma unroll
    for (int k = 0; k < 4; ++k) {
        int v = vbase + threadIdx.x + k * P1_THREADS;
        if (v < VEC_E) {
            int4 s = s4[v];
            float4 ww = w4[v];
            int4 d = dc[k];
            int bin, dl, r;
            bin = d.x >> 8; dl = d.x & 255;
            r = atomicAdd(&h[bin], 1);
            entries[claim[bin] + r] = make_float2(__int_as_float(s.x | (dl << 17)), ww.x);
            bin = d.y >> 8; dl = d.y & 255;
            r = atomicAdd(&h[bin], 1);
            entries[claim[bin] + r] = make_float2(__int_as_float(s.y | (dl << 17)), ww.y);
            bin = d.z >> 8; dl = d.z & 255;
            r = atomicAdd(&h[bin], 1);
            entries[claim[bin] + r] = make_float2(__int_as_float(s.z | (dl << 17)), ww.z);
            bin = d.w >> 8; dl = d.w & 255;
            r = atomicAdd(&h[bin], 1);
            entries[claim[bin] + r] = make_float2(__int_as_float(s.w | (dl << 17)), ww.w);
        }
    }
}

// Phase 2a: dinv per bucket via LDS float accumulation
__global__ void __launch_bounds__(1024)
degree_kernel(const float2* __restrict__ entries, const int* __restrict__ basea,
              float* __restrict__ dinv) {
    __shared__ float wsum[NODES_PER_B];
    if (threadIdx.x < NODES_PER_B) wsum[threadIdx.x] = 0.f;
    __syncthreads();
    int b = blockIdx.x;
    int lo = basea[b], hi = basea[b + 1];
    for (int j = lo + threadIdx.x; j < hi; j += 1024) {
        float2 e = entries[j];
        atomicAdd(&wsum[__float_as_int(e.x) >> 17], e.y);
    }
    __syncthreads();
    if (threadIdx.x < NODES_PER_B) {
        int n = (b << 8) + threadIdx.x;
        if (n < N_NODES) dinv[n] = rsqrtf(1.0f + wsum[threadIdx.x]);
    }
}

// Phase 2b: y[n][0..11] = dinv[n]*x[n][:], padded to 16 floats (64B-aligned rows)
__global__ void y_kernel(const float* __restrict__ x, const float* __restrict__ dinv,
                         float* __restrict__ y) {
    int n = blockIdx.x * blockDim.x + threadIdx.x;
    if (n >= N_NODES) return;
    float din = dinv[n];
    const float4* xn = (const float4*)(x + (size_t)n * T_P);
    float4 a0 = xn[0], a1 = xn[1], a2 = xn[2];
    a0.x *= din; a0.y *= din; a0.z *= din; a0.w *= din;
    a1.x *= din; a1.y *= din; a1.z *= din; a1.w *= din;
    a2.x *= din; a2.y *= din; a2.z *= din; a2.w *= din;
    float4* yn = (float4*)(y + ((size_t)n << 4));
    yn[0] = a0; yn[1] = a1; yn[2] = a2;
}

// Phase 2c: per-bucket aggregation in LDS + fused gate math + head dot.
// lagg init = y[n] (=dinv*x); edges add w_e*y[s]; final a = dinv[n]*lagg.
__global__ void __launch_bounds__(1024)
fused_agg_kernel(const float2* __restrict__ entries, const int* __restrict__ basea,
                 const float* __restrict__ dinv, const float* __restrict__ y,
                 const float* __restrict__ P, const float* __restrict__ head_w,
                 const float* __restrict__ head_b, float* __restrict__ out) {
    __shared__ float lagg[NODES_PER_B * LSTR];
    int b = blockIdx.x;
    int nbase = b << 8;
    for (int i = threadIdx.x; i < NODES_PER_B * T_P; i += 1024) {
        int nl = i / T_P;
        int t = i - nl * T_P;
        int n = nbase + nl;
        lagg[nl * LSTR + t] = (n < N_NODES) ? y[((size_t)n << 4) + t] : 0.f;
    }
    __syncthreads();
    int lo = basea[b], hi = basea[b + 1];
    for (int j = lo + threadIdx.x; j < hi; j += 1024) {
        float2 e = entries[j];
        int u = __float_as_int(e.x);
        int s = u & 0x1FFFF;
        int dl = u >> 17;
        float coef = e.y;
        const float4* ys = (const float4*)(y + ((size_t)s << 4));  // one 64B line
        float4 x0 = ys[0], x1 = ys[1], x2 = ys[2];
        float* L = &lagg[dl * LSTR];
        atomicAdd(&L[0],  coef * x0.x); atomicAdd(&L[1],  coef * x0.y);
        atomicAdd(&L[2],  coef * x0.z); atomicAdd(&L[3],  coef * x0.w);
        atomicAdd(&L[4],  coef * x1.x); atomicAdd(&L[5],  coef * x1.y);
        atomicAdd(&L[6],  coef * x1.z); atomicAdd(&L[7],  coef * x1.w);
        atomicAdd(&L[8],  coef * x2.x); atomicAdd(&L[9],  coef * x2.y);
        atomicAdd(&L[10], coef * x2.z); atomicAdd(&L[11], coef * x2.w);
    }
    __syncthreads();
    // epilogue: 1024 threads = 32 nodes x 32 channels per iteration
    int o = threadIdx.x & 31;
    int ng = threadIdx.x >> 5;          // 0..31
    float Az = P[16 + o], Bz = P[48 + o], Ah = P[80 + o], Bh = P[112 + o];
    float hwv = head_w[o];
    float hbv = head_b[0];
    float pr[T_P];
#pragma unroll
    for (int t = 0; t < T_P; ++t) pr[t] = P[t];
#pragma unroll
    for (int k = 0; k < 8; ++k) {
        int nl = k * 32 + ng;
        int n = nbase + nl;
        if (n < N_NODES) {
            float din = dinv[n];
            float h = 0.f;
#pragma unroll
            for (int t = 0; t < T_P; ++t) {
                float a = din * lagg[nl * LSTR + t];
                float oz = 1.f / (1.f + __expf(a * Az + Bz));      // 1 - sigmoid(u)
                float vv = a * Ah + Bh;
                float th = 1.f - 2.f / (1.f + __expf(2.f * vv));   // tanh
                h += pr[t] * oz * th;
            }
            h = fmaxf(h, 0.f) * hwv;
#pragma unroll
            for (int m = 16; m > 0; m >>= 1) h += __shfl_xor(h, m, 32);
            if (o == 0) out[n] = h + hbv;
        }
    }
}

extern "C" void kernel_launch(void* const* d_in, const int* in_sizes, int n_in,
                              void* d_out, int out_size, void* d_ws, size_t ws_size,
                              hipStream_t stream) {
    const float* x    = (const float*)d_in[0];
    const int*   ei   = (const int*)d_in[1];      // [2, E]: src = ei, dst = ei + E
    const float* ew   = (const float*)d_in[2];
    const float* w_z  = (const float*)d_in[3];
    const float* b_z  = (const float*)d_in[4];
    const float* w_h  = (const float*)d_in[7];
    const float* b_h  = (const float*)d_in[8];
    const float* lw_z = (const float*)d_in[9];
    const float* lb_z = (const float*)d_in[10];
    const float* lw_h = (const float*)d_in[13];
    const float* lb_h = (const float*)d_in[14];
    const float* att  = (const float*)d_in[15];
    const float* hw   = (const float*)d_in[16];
    const float* hb   = (const float*)d_in[17];
    float* out = (float*)d_out;

    float* wsf    = (float*)d_ws;
    float* P      = wsf;                           // 256
    float* dinv   = P + 256;                       // N
    int*   cnt    = (int*)(dinv + N_NODES);        // NB
    int*   basea  = cnt + NB;                      // NB+1
    int*   cursor = basea + NB + 1;                // NB
    float* y      = wsf + 256 + N_NODES + NB + (NB + 1) + NB + 6;  // 16-float aligned rows
    float2* entries = (float2*)(y + (size_t)N_NODES * 16);

    const int* srcp = ei;
    const int* dstp = ei + E_EDGES;

    zero_cnt_kernel<<<1, 512, 0, stream>>>(cnt);
    params_kernel<<<1, 64, 0, stream>>>(w_z, b_z, w_h, b_h, lw_z, lb_z, lw_h, lb_h, att, P);
    bucket_count_kernel<<<NBLK1, P1_THREADS, 0, stream>>>(dstp, cnt);
    bucket_scan_kernel<<<1, 512, 0, stream>>>(cnt, basea, cursor);
    bucket_scatter_kernel<<<NBLK1, P1_THREADS, 0, stream>>>(srcp, dstp, ew, cursor, entries);
    degree_kernel<<<NB, 1024, 0, stream>>>(entries, basea, dinv);
    y_kernel<<<(N_NODES + 255) / 256, 256, 0, stream>>>(x, dinv, y);
    fused_agg_kernel<<<NB, 1024, 0, stream>>>(entries, basea, dinv, y, P, hw, hb, out);
}

// Round 3
// 466.314 us; speedup vs baseline: 1.0169x; 1.0169x over previous
//
#include <hip/hip_runtime.h>

#define N_NODES 100000
#define T_P 12
#define C_H 32
#define E_EDGES 3200000

#define NODES_PER_B 128
#define NB 782                    // ceil(100000/128) buckets
#define LSTR 13                   // LDS row stride (odd -> bank spread)

#define VEC_E (E_EDGES / 4)       // 800000 int4/float4 vectors
#define P1_THREADS 512
#define P1_VECS 2048              // vectors per block in phase 1
#define NBLK1 ((VEC_E + P1_VECS - 1) / P1_VECS)   // 391

// ws layout (4-byte units from d_ws):
//   P[256] | dinv[N] | cnt[NB] | base[NB+1] | cursor[NB] | pad | y[N*16] | entries[E]{float2}

__global__ void zero_cnt_kernel(int* __restrict__ cnt) {
    int i = threadIdx.x;
    if (i < NB) cnt[i] = 0;
}

__global__ void params_kernel(const float* __restrict__ wz, const float* __restrict__ bz,
                              const float* __restrict__ wh, const float* __restrict__ bh,
                              const float* __restrict__ lwz, const float* __restrict__ lbz,
                              const float* __restrict__ lwh, const float* __restrict__ lbh,
                              const float* __restrict__ att, float* __restrict__ P) {
    int o = threadIdx.x;
    if (o < C_H) {
        float az = 0.f, bzv = 0.f, ah = 0.f, bhv = 0.f;
        for (int c = 0; c < C_H; ++c) {
            float lz = lwz[o * 2 * C_H + c];
            float lh = lwh[o * 2 * C_H + c];
            az += wz[c] * lz;  bzv += bz[c] * lz;
            ah += wh[c] * lh;  bhv += bh[c] * lh;
        }
        P[16 + o]  = az;  P[48 + o]  = bzv + lbz[o];
        P[80 + o]  = ah;  P[112 + o] = bhv + lbh[o];
    }
    if (o == 0) {
        float m = -1e30f;
        for (int t = 0; t < T_P; ++t) m = fmaxf(m, att[t]);
        float e[T_P], s = 0.f;
        for (int t = 0; t < T_P; ++t) { e[t] = __expf(att[t] - m); s += e[t]; }
        float inv = 1.0f / s;
        for (int t = 0; t < T_P; ++t) P[t] = e[t] * inv;
    }
}

// Phase 1a: coarse histogram of dst>>7 with LDS privatization.
__global__ void bucket_count_kernel(const int* __restrict__ dst, int* __restrict__ cnt) {
    __shared__ int h[NB];
    for (int i = threadIdx.x; i < NB; i += P1_THREADS) h[i] = 0;
    __syncthreads();
    const int4* d4 = (const int4*)dst;
    int vbase = blockIdx.x * P1_VECS;
#pragma unroll
    for (int k = 0; k < 4; ++k) {
        int v = vbase + threadIdx.x + k * P1_THREADS;
        if (v < VEC_E) {
            int4 d = d4[v];
            atomicAdd(&h[d.x >> 7], 1);
            atomicAdd(&h[d.y >> 7], 1);
            atomicAdd(&h[d.z >> 7], 1);
            atomicAdd(&h[d.w >> 7], 1);
        }
    }
    __syncthreads();
    for (int i = threadIdx.x; i < NB; i += P1_THREADS) {
        int c = h[i];
        if (c) atomicAdd(&cnt[i], c);
    }
}

// exclusive scan of NB bucket counts -> base + cursor copy
__global__ void __launch_bounds__(1024)
bucket_scan_kernel(const int* __restrict__ cnt, int* __restrict__ basea,
                   int* __restrict__ cursor) {
    __shared__ int buf[1024];
    int tid = threadIdx.x;
    int v = (tid < NB) ? cnt[tid] : 0;
    buf[tid] = v;
    __syncthreads();
    for (int d = 1; d < 1024; d <<= 1) {
        int t = (tid >= d) ? buf[tid - d] : 0;
        __syncthreads();
        buf[tid] += t;
        __syncthreads();
    }
    if (tid < NB) {
        int ex = buf[tid] - v;
        basea[tid] = ex;
        cursor[tid] = ex;
    }
    if (tid == 0) basea[NB] = E_EDGES;
}

// Phase 1b: per-block recount -> claim ranges -> scatter {src | d_local<<17, w}
__global__ void bucket_scatter_kernel(const int* __restrict__ src, const int* __restrict__ dst,
                                      const float* __restrict__ w, int* __restrict__ cursor,
                                      float2* __restrict__ entries) {
    __shared__ int h[NB];
    __shared__ int claim[NB];
    for (int i = threadIdx.x; i < NB; i += P1_THREADS) h[i] = 0;
    __syncthreads();
    const int4* d4 = (const int4*)dst;
    int vbase = blockIdx.x * P1_VECS;
    int4 dc[4];
#pragma unroll
    for (int k = 0; k < 4; ++k) {
        int v = vbase + threadIdx.x + k * P1_THREADS;
        if (v < VEC_E) {
            int4 d = d4[v];
            dc[k] = d;
            atomicAdd(&h[d.x >> 7], 1);
            atomicAdd(&h[d.y >> 7], 1);
            atomicAdd(&h[d.z >> 7], 1);
            atomicAdd(&h[d.w >> 7], 1);
        }
    }
    __syncthreads();
    for (int i = threadIdx.x; i < NB; i += P1_THREADS) {
        int c = h[i];
        claim[i] = c ? atomicAdd(&cursor[i], c) : 0;
    }
    __syncthreads();
    for (int i = threadIdx.x; i < NB; i += P1_THREADS) h[i] = 0;   // reuse as rank counter
    __syncthreads();
    const int4* s4 = (const int4*)src;
    const float4* w4 = (const float4*)w;
#pragma unroll
    for (int k = 0; k < 4; ++k) {
        int v = vbase + threadIdx.x + k * P1_THREADS;
        if (v < VEC_E) {
            int4 s = s4[v];
            float4 ww = w4[v];
            int4 d = dc[k];
            int bin, dl, r;
            bin = d.x >> 7; dl = d.x & 127;
            r = atomicAdd(&h[bin], 1);
            entries[claim[bin] + r] = make_float2(__int_as_float(s.x | (dl << 17)), ww.x);
            bin = d.y >> 7; dl = d.y & 127;
            r = atomicAdd(&h[bin], 1);
            entries[claim[bin] + r] = make_float2(__int_as_float(s.y | (dl << 17)), ww.y);
            bin = d.z >> 7; dl = d.z & 127;
            r = atomicAdd(&h[bin], 1);
            entries[claim[bin] + r] = make_float2(__int_as_float(s.z | (dl << 17)), ww.z);
            bin = d.w >> 7; dl = d.w & 127;
            r = atomicAdd(&h[bin], 1);
            entries[claim[bin] + r] = make_float2(__int_as_float(s.w | (dl << 17)), ww.w);
        }
    }
}

// Phase 2a: dinv per bucket via LDS float accumulation
__global__ void __launch_bounds__(1024)
degree_kernel(const float2* __restrict__ entries, const int* __restrict__ basea,
              float* __restrict__ dinv) {
    __shared__ float wsum[NODES_PER_B];
    if (threadIdx.x < NODES_PER_B) wsum[threadIdx.x] = 0.f;
    __syncthreads();
    int b = blockIdx.x;
    int lo = basea[b], hi = basea[b + 1];
    for (int j = lo + threadIdx.x; j < hi; j += 1024) {
        float2 e = entries[j];
        atomicAdd(&wsum[(__float_as_int(e.x) >> 17) & 127], e.y);
    }
    __syncthreads();
    if (threadIdx.x < NODES_PER_B) {
        int n = (b << 7) + threadIdx.x;
        if (n < N_NODES) dinv[n] = rsqrtf(1.0f + wsum[threadIdx.x]);
    }
}

// Phase 2b: y[n][0..11] = dinv[n]*x[n][:], padded to 16 floats (zeroed pad, 64B rows)
__global__ void y_kernel(const float* __restrict__ x, const float* __restrict__ dinv,
                         float* __restrict__ y) {
    int n = blockIdx.x * blockDim.x + threadIdx.x;
    if (n >= N_NODES) return;
    float din = dinv[n];
    const float4* xn = (const float4*)(x + (size_t)n * T_P);
    float4 a0 = xn[0], a1 = xn[1], a2 = xn[2];
    a0.x *= din; a0.y *= din; a0.z *= din; a0.w *= din;
    a1.x *= din; a1.y *= din; a1.z *= din; a1.w *= din;
    a2.x *= din; a2.y *= din; a2.z *= din; a2.w *= din;
    float4* yn = (float4*)(y + ((size_t)n << 4));
    yn[0] = a0; yn[1] = a1; yn[2] = a2;
    yn[3] = make_float4(0.f, 0.f, 0.f, 0.f);
}

// Phase 2c: per-bucket aggregation in LDS + fused gate math + head dot.
// 4 lanes per edge: lane sub loads y[s] floats [4*sub .. 4*sub+3] — the edge's
// whole 64B row is consumed by the single gather instruction that fetches it
// (no L1 retention needed; 1 line-touch per edge instead of 3).
__global__ void __launch_bounds__(1024)
fused_agg_kernel(const float2* __restrict__ entries, const int* __restrict__ basea,
                 const float* __restrict__ dinv, const float* __restrict__ y,
                 const float* __restrict__ P, const float* __restrict__ head_w,
                 const float* __restrict__ head_b, float* __restrict__ out) {
    __shared__ float lagg[NODES_PER_B * LSTR];
    int b = blockIdx.x;
    int nbase = b << 7;
    for (int i = threadIdx.x; i < NODES_PER_B * T_P; i += 1024) {
        int nl = i / T_P;
        int t = i - nl * T_P;
        int n = nbase + nl;
        lagg[nl * LSTR + t] = (n < N_NODES) ? y[((size_t)n << 4) + t] : 0.f;
    }
    __syncthreads();
    int lo = basea[b], hi = basea[b + 1];
    int g = threadIdx.x >> 2;          // edge group 0..255
    int sub = threadIdx.x & 3;         // quarter-row 0..3 (3 = zero pad)
    for (int j = lo + g; j < hi; j += 256) {
        float2 e = entries[j];
        int u = __float_as_int(e.x);
        int s = u & 0x1FFFF;
        int dl = (u >> 17) & 127;
        float4 v = *(const float4*)(y + ((size_t)s << 4) + (sub << 2));
        float c = e.y;
        if (sub < 3) {
            float* L = &lagg[dl * LSTR + (sub << 2)];
            atomicAdd(&L[0], c * v.x);
            atomicAdd(&L[1], c * v.y);
            atomicAdd(&L[2], c * v.z);
            atomicAdd(&L[3], c * v.w);
        }
    }
    __syncthreads();
    // epilogue: 1024 threads = 32 node-groups x 32 channels; 128 nodes -> 4 iters
    int o = threadIdx.x & 31;
    int ng = threadIdx.x >> 5;          // 0..31
    float Az = P[16 + o], Bz = P[48 + o], Ah = P[80 + o], Bh = P[112 + o];
    float hwv = head_w[o];
    float hbv = head_b[0];
    float pr[T_P];
#pragma unroll
    for (int t = 0; t < T_P; ++t) pr[t] = P[t];
#pragma unroll
    for (int k = 0; k < 4; ++k) {
        int nl = k * 32 + ng;
        int n = nbase + nl;
        if (n < N_NODES) {
            float din = dinv[n];
            float h = 0.f;
#pragma unroll
            for (int t = 0; t < T_P; ++t) {
                float a = din * lagg[nl * LSTR + t];
                float oz = 1.f / (1.f + __expf(a * Az + Bz));      // 1 - sigmoid(u)
                float vv = a * Ah + Bh;
                float th = 1.f - 2.f / (1.f + __expf(2.f * vv));   // tanh
                h += pr[t] * oz * th;
            }
            h = fmaxf(h, 0.f) * hwv;
#pragma unroll
            for (int m = 16; m > 0; m >>= 1) h += __shfl_xor(h, m, 32);
            if (o == 0) out[n] = h + hbv;
        }
    }
}

extern "C" void kernel_launch(void* const* d_in, const int* in_sizes, int n_in,
                              void* d_out, int out_size, void* d_ws, size_t ws_size,
                              hipStream_t stream) {
    const float* x    = (const float*)d_in[0];
    const int*   ei   = (const int*)d_in[1];      // [2, E]: src = ei, dst = ei + E
    const float* ew   = (const float*)d_in[2];
    const float* w_z  = (const float*)d_in[3];
    const float* b_z  = (const float*)d_in[4];
    const float* w_h  = (const float*)d_in[7];
    const float* b_h  = (const float*)d_in[8];
    const float* lw_z = (const float*)d_in[9];
    const float* lb_z = (const float*)d_in[10];
    const float* lw_h = (const float*)d_in[13];
    const float* lb_h = (const float*)d_in[14];
    const float* att  = (const float*)d_in[15];
    const float* hw   = (const float*)d_in[16];
    const float* hb   = (const float*)d_in[17];
    float* out = (float*)d_out;

    float* wsf    = (float*)d_ws;
    float* P      = wsf;                           // 256
    float* dinv   = P + 256;                       // N
    int*   cnt    = (int*)(dinv + N_NODES);        // NB
    int*   basea  = cnt + NB;                      // NB+1
    int*   cursor = basea + NB + 1;                // NB
    // used so far: 256 + 100000 + 782 + 783 + 782 = 102603 -> round up to 102608
    float* y      = wsf + 102608;                  // N*16 floats, 64B-aligned rows
    float2* entries = (float2*)(y + (size_t)N_NODES * 16);

    const int* srcp = ei;
    const int* dstp = ei + E_EDGES;

    zero_cnt_kernel<<<1, 1024, 0, stream>>>(cnt);
    params_kernel<<<1, 64, 0, stream>>>(w_z, b_z, w_h, b_h, lw_z, lb_z, lw_h, lb_h, att, P);
    bucket_count_kernel<<<NBLK1, P1_THREADS, 0, stream>>>(dstp, cnt);
    bucket_scan_kernel<<<1, 1024, 0, stream>>>(cnt, basea, cursor);
    bucket_scatter_kernel<<<NBLK1, P1_THREADS, 0, stream>>>(srcp, dstp, ew, cursor, entries);
    degree_kernel<<<NB, 1024, 0, stream>>>(entries, basea, dinv);
    y_kernel<<<(N_NODES + 255) / 256, 256, 0, stream>>>(x, dinv, y);
    fused_agg_kernel<<<NB, 1024, 0, stream>>>(entries, basea, dinv, y, P, hw, hb, out);
}

// Round 4
// 319.831 us; speedup vs baseline: 1.4827x; 1.4580x over previous
//
#include <hip/hip_runtime.h>

#define N_NODES 100000
#define T_P 12
#define C_H 32
#define E_EDGES 3200000

#define NODES_PER_B 128
#define NB 782                    // ceil(100000/128) buckets

#define VEC_E (E_EDGES / 4)       // 800000 int4/float4 vectors
#define P1_THREADS 512
#define P1_VECS 2048              // vectors per block in phase 1
#define NBLK1 ((VEC_E + P1_VECS - 1) / P1_VECS)   // 391

#define MAX_BE 5120               // staged entries cap per bucket (mean 4096, sd 64)

// ws layout (4-byte units from d_ws):
//   P[256] | dinv[N] | cnt[NB] | basea[NB+1] | cursor[NB] | node_off[N+1] | pad |
//   y[N*16] | agg[N*12] | entries[E]{float2}   -- total ~37.6 MB

__global__ void zero_cnt_kernel(int* __restrict__ cnt) {
    int i = threadIdx.x;
    if (i < NB) cnt[i] = 0;
}

__global__ void params_kernel(const float* __restrict__ wz, const float* __restrict__ bz,
                              const float* __restrict__ wh, const float* __restrict__ bh,
                              const float* __restrict__ lwz, const float* __restrict__ lbz,
                              const float* __restrict__ lwh, const float* __restrict__ lbh,
                              const float* __restrict__ att, float* __restrict__ P) {
    int o = threadIdx.x;
    if (o < C_H) {
        float az = 0.f, bzv = 0.f, ah = 0.f, bhv = 0.f;
        for (int c = 0; c < C_H; ++c) {
            float lz = lwz[o * 2 * C_H + c];
            float lh = lwh[o * 2 * C_H + c];
            az += wz[c] * lz;  bzv += bz[c] * lz;
            ah += wh[c] * lh;  bhv += bh[c] * lh;
        }
        P[16 + o]  = az;  P[48 + o]  = bzv + lbz[o];
        P[80 + o]  = ah;  P[112 + o] = bhv + lbh[o];
    }
    if (o == 0) {
        float m = -1e30f;
        for (int t = 0; t < T_P; ++t) m = fmaxf(m, att[t]);
        float e[T_P], s = 0.f;
        for (int t = 0; t < T_P; ++t) { e[t] = __expf(att[t] - m); s += e[t]; }
        float inv = 1.0f / s;
        for (int t = 0; t < T_P; ++t) P[t] = e[t] * inv;
    }
}

// Phase 1a: coarse histogram of dst>>7 with LDS privatization.
__global__ void bucket_count_kernel(const int* __restrict__ dst, int* __restrict__ cnt) {
    __shared__ int h[NB];
    for (int i = threadIdx.x; i < NB; i += P1_THREADS) h[i] = 0;
    __syncthreads();
    const int4* d4 = (const int4*)dst;
    int vbase = blockIdx.x * P1_VECS;
#pragma unroll
    for (int k = 0; k < 4; ++k) {
        int v = vbase + threadIdx.x + k * P1_THREADS;
        if (v < VEC_E) {
            int4 d = d4[v];
            atomicAdd(&h[d.x >> 7], 1);
            atomicAdd(&h[d.y >> 7], 1);
            atomicAdd(&h[d.z >> 7], 1);
            atomicAdd(&h[d.w >> 7], 1);
        }
    }
    __syncthreads();
    for (int i = threadIdx.x; i < NB; i += P1_THREADS) {
        int c = h[i];
        if (c) atomicAdd(&cnt[i], c);
    }
}

// exclusive scan of NB bucket counts -> basea + cursor copy
__global__ void __launch_bounds__(1024)
bucket_scan_kernel(const int* __restrict__ cnt, int* __restrict__ basea,
                   int* __restrict__ cursor) {
    __shared__ int buf[1024];
    int tid = threadIdx.x;
    int v = (tid < NB) ? cnt[tid] : 0;
    buf[tid] = v;
    __syncthreads();
    for (int d = 1; d < 1024; d <<= 1) {
        int t = (tid >= d) ? buf[tid - d] : 0;
        __syncthreads();
        buf[tid] += t;
        __syncthreads();
    }
    if (tid < NB) {
        int ex = buf[tid] - v;
        basea[tid] = ex;
        cursor[tid] = ex;
    }
    if (tid == 0) basea[NB] = E_EDGES;
}

// Phase 1b: per-block recount -> claim ranges -> scatter {src | d_local<<17, w}
__global__ void bucket_scatter_kernel(const int* __restrict__ src, const int* __restrict__ dst,
                                      const float* __restrict__ w, int* __restrict__ cursor,
                                      float2* __restrict__ entries) {
    __shared__ int h[NB];
    __shared__ int claim[NB];
    for (int i = threadIdx.x; i < NB; i += P1_THREADS) h[i] = 0;
    __syncthreads();
    const int4* d4 = (const int4*)dst;
    int vbase = blockIdx.x * P1_VECS;
    int4 dc[4];
#pragma unroll
    for (int k = 0; k < 4; ++k) {
        int v = vbase + threadIdx.x + k * P1_THREADS;
        if (v < VEC_E) {
            int4 d = d4[v];
            dc[k] = d;
            atomicAdd(&h[d.x >> 7], 1);
            atomicAdd(&h[d.y >> 7], 1);
            atomicAdd(&h[d.z >> 7], 1);
            atomicAdd(&h[d.w >> 7], 1);
        }
    }
    __syncthreads();
    for (int i = threadIdx.x; i < NB; i += P1_THREADS) {
        int c = h[i];
        claim[i] = c ? atomicAdd(&cursor[i], c) : 0;
    }
    __syncthreads();
    for (int i = threadIdx.x; i < NB; i += P1_THREADS) h[i] = 0;   // reuse as rank counter
    __syncthreads();
    const int4* s4 = (const int4*)src;
    const float4* w4 = (const float4*)w;
#pragma unroll
    for (int k = 0; k < 4; ++k) {
        int v = vbase + threadIdx.x + k * P1_THREADS;
        if (v < VEC_E) {
            int4 s = s4[v];
            float4 ww = w4[v];
            int4 d = dc[k];
            int bin, dl, r;
            bin = d.x >> 7; dl = d.x & 127;
            r = atomicAdd(&h[bin], 1);
            entries[claim[bin] + r] = make_float2(__int_as_float(s.x | (dl << 17)), ww.x);
            bin = d.y >> 7; dl = d.y & 127;
            r = atomicAdd(&h[bin], 1);
            entries[claim[bin] + r] = make_float2(__int_as_float(s.y | (dl << 17)), ww.y);
            bin = d.z >> 7; dl = d.z & 127;
            r = atomicAdd(&h[bin], 1);
            entries[claim[bin] + r] = make_float2(__int_as_float(s.z | (dl << 17)), ww.z);
            bin = d.w >> 7; dl = d.w & 127;
            r = atomicAdd(&h[bin], 1);
            entries[claim[bin] + r] = make_float2(__int_as_float(s.w | (dl << 17)), ww.w);
        }
    }
}

// Phase 1c: per-bucket in-place node-sort (stage in LDS) + fused degree/dinv.
// Produces: entries[node_off[n] .. node_off[n+1]) = {src_bits, w} for node n.
__global__ void __launch_bounds__(1024)
reorder_kernel(float2* __restrict__ entries, const int* __restrict__ basea,
               int* __restrict__ node_off, float* __restrict__ dinv) {
    __shared__ float2 stage[MAX_BE];        // 40 KB
    __shared__ int   cnt[NODES_PER_B];
    __shared__ float wsum[NODES_PER_B];
    __shared__ int   off[NODES_PER_B];
    __shared__ int   rnk[NODES_PER_B];
    int tid = threadIdx.x;
    int b = blockIdx.x;
    int lo = basea[b], hi = basea[b + 1];
    int ne = hi - lo;
    if (tid < NODES_PER_B) { cnt[tid] = 0; wsum[tid] = 0.f; }
    __syncthreads();
    // load to LDS + histogram + weight sums
    for (int k = tid; k < ne; k += 1024) {
        float2 e = entries[lo + k];
        if (k < MAX_BE) stage[k] = e;
        int dl = (__float_as_int(e.x) >> 17) & 127;
        atomicAdd(&cnt[dl], 1);
        atomicAdd(&wsum[dl], e.y);
    }
    __syncthreads();
    if (tid < NODES_PER_B) off[tid] = cnt[tid];
    __syncthreads();
    for (int d = 1; d < NODES_PER_B; d <<= 1) {
        int t = (tid >= d && tid < NODES_PER_B) ? off[tid - d] : 0;
        __syncthreads();
        if (tid < NODES_PER_B) off[tid] += t;
        __syncthreads();
    }
    if (tid < NODES_PER_B) {
        int ex = off[tid] - cnt[tid];           // exclusive
        rnk[tid] = ex;
        int n = (b << 7) + tid;
        if (n <= N_NODES) node_off[n] = lo + ex;
        if (n < N_NODES) dinv[n] = rsqrtf(1.0f + wsum[tid]);
    }
    __syncthreads();
    // scatter back node-sorted (strip dl from payload)
    for (int k = tid; k < ne; k += 1024) {
        float2 e = stage[k < MAX_BE ? k : 0];
        int u = __float_as_int(e.x);
        int dl = (u >> 17) & 127;
        int s = u & 0x1FFFF;
        int r = atomicAdd(&rnk[dl], 1);
        entries[lo + r] = make_float2(__int_as_float(s), e.y);
    }
}

// Phase 2a: y[n][0..11] = dinv[n]*x[n][:], padded to 16 floats (64B-aligned rows)
__global__ void y_kernel(const float* __restrict__ x, const float* __restrict__ dinv,
                         float* __restrict__ y) {
    int n = blockIdx.x * blockDim.x + threadIdx.x;
    if (n >= N_NODES) return;
    float din = dinv[n];
    const float4* xn = (const float4*)(x + (size_t)n * T_P);
    float4 a0 = xn[0], a1 = xn[1], a2 = xn[2];
    a0.x *= din; a0.y *= din; a0.z *= din; a0.w *= din;
    a1.x *= din; a1.y *= din; a1.z *= din; a1.w *= din;
    a2.x *= din; a2.y *= din; a2.z *= din; a2.w *= din;
    float4* yn = (float4*)(y + ((size_t)n << 4));
    yn[0] = a0; yn[1] = a1; yn[2] = a2;
    yn[3] = make_float4(0.f, 0.f, 0.f, 0.f);
}

// Phase 2b: per-node register-accumulating gather (no atomics in hot loop).
// agg[n,:] = dinv[n] * ( y[n] + sum_e w_e * y[src_e] )
__global__ void gather_kernel(const int* __restrict__ node_off, const float2* __restrict__ entries,
                              const float* __restrict__ dinv, const float* __restrict__ y,
                              float* __restrict__ agg) {
    int n = blockIdx.x * blockDim.x + threadIdx.x;
    if (n >= N_NODES) return;
    int b = node_off[n], e = node_off[n + 1];
    const float4* yn = (const float4*)(y + ((size_t)n << 4));
    float4 a0 = yn[0], a1 = yn[1], a2 = yn[2];
    for (int i = b; i < e; ++i) {
        float2 ent = entries[i];
        int s = __float_as_int(ent.x);
        float c = ent.y;
        const float4* ys = (const float4*)(y + ((size_t)s << 4));  // one 64B line
        float4 x0 = ys[0], x1 = ys[1], x2 = ys[2];
        a0.x += c * x0.x; a0.y += c * x0.y; a0.z += c * x0.z; a0.w += c * x0.w;
        a1.x += c * x1.x; a1.y += c * x1.y; a1.z += c * x1.z; a1.w += c * x1.w;
        a2.x += c * x2.x; a2.y += c * x2.y; a2.z += c * x2.z; a2.w += c * x2.w;
    }
    float din = dinv[n];
    a0.x *= din; a0.y *= din; a0.z *= din; a0.w *= din;
    a1.x *= din; a1.y *= din; a1.z *= din; a1.w *= din;
    a2.x *= din; a2.y *= din; a2.z *= din; a2.w *= din;
    float4* an = (float4*)(agg + (size_t)n * T_P);
    an[0] = a0; an[1] = a1; an[2] = a2;
}

// Phase 3: gate math + attention sum + head (32 lanes per node)
__global__ void final_kernel(const float* __restrict__ agg, const float* __restrict__ P,
                             const float* __restrict__ head_w, const float* __restrict__ head_b,
                             float* __restrict__ out) {
    int tid = blockIdx.x * blockDim.x + threadIdx.x;
    int n = tid >> 5;         // 32 lanes per node (channel o = lane)
    int o = tid & 31;
    if (n >= N_NODES) return;
    float Az = P[16 + o], Bz = P[48 + o], Ah = P[80 + o], Bh = P[112 + o];
    float h = 0.f;
#pragma unroll
    for (int t = 0; t < T_P; ++t) {
        float a = agg[(size_t)n * T_P + t];
        float oz = 1.f / (1.f + __expf(a * Az + Bz));          // 1 - sigmoid(u)
        float v  = a * Ah + Bh;
        float th = 1.f - 2.f / (1.f + __expf(2.f * v));        // tanh via exp
        h += P[t] * oz * th;
    }
    h = fmaxf(h, 0.f) * head_w[o];
#pragma unroll
    for (int m = 16; m > 0; m >>= 1) h += __shfl_xor(h, m, 32);
    if (o == 0) out[n] = h + head_b[0];
}

extern "C" void kernel_launch(void* const* d_in, const int* in_sizes, int n_in,
                              void* d_out, int out_size, void* d_ws, size_t ws_size,
                              hipStream_t stream) {
    const float* x    = (const float*)d_in[0];
    const int*   ei   = (const int*)d_in[1];      // [2, E]: src = ei, dst = ei + E
    const float* ew   = (const float*)d_in[2];
    const float* w_z  = (const float*)d_in[3];
    const float* b_z  = (const float*)d_in[4];
    const float* w_h  = (const float*)d_in[7];
    const float* b_h  = (const float*)d_in[8];
    const float* lw_z = (const float*)d_in[9];
    const float* lb_z = (const float*)d_in[10];
    const float* lw_h = (const float*)d_in[13];
    const float* lb_h = (const float*)d_in[14];
    const float* att  = (const float*)d_in[15];
    const float* hw   = (const float*)d_in[16];
    const float* hb   = (const float*)d_in[17];
    float* out = (float*)d_out;

    float* wsf    = (float*)d_ws;
    float* P      = wsf;                           // 256
    float* dinv   = P + 256;                       // N          @256
    int*   cnt    = (int*)(dinv + N_NODES);        // NB         @100256
    int*   basea  = cnt + NB;                      // NB+1       @101038
    int*   cursor = basea + NB + 1;                // NB         @101821
    int*   node_off = cursor + NB;                 // N+1        @102603
    float* y      = wsf + 202608;                  // N*16, 64B-aligned rows
    float* agg    = y + (size_t)N_NODES * 16;      // N*12       @1802608
    float2* entries = (float2*)(agg + (size_t)N_NODES * T_P);    // E float2 @3002608

    const int* srcp = ei;
    const int* dstp = ei + E_EDGES;

    zero_cnt_kernel<<<1, 1024, 0, stream>>>(cnt);
    params_kernel<<<1, 64, 0, stream>>>(w_z, b_z, w_h, b_h, lw_z, lb_z, lw_h, lb_h, att, P);
    bucket_count_kernel<<<NBLK1, P1_THREADS, 0, stream>>>(dstp, cnt);
    bucket_scan_kernel<<<1, 1024, 0, stream>>>(cnt, basea, cursor);
    bucket_scatter_kernel<<<NBLK1, P1_THREADS, 0, stream>>>(srcp, dstp, ew, cursor, entries);
    reorder_kernel<<<NB, 1024, 0, stream>>>(entries, basea, node_off, dinv);
    y_kernel<<<(N_NODES + 255) / 256, 256, 0, stream>>>(x, dinv, y);
    gather_kernel<<<(N_NODES + 255) / 256, 256, 0, stream>>>(node_off, entries, dinv, y, agg);
    final_kernel<<<(N_NODES * C_H + 255) / 256, 256, 0, stream>>>(agg, P, hw, hb, out);
}